// Round 12
// baseline (139.692 us; speedup 1.0000x reference)
//
#include <hip/hip_runtime.h>
#include <hip/hip_bf16.h>
#include <math.h>

typedef __attribute__((ext_vector_type(8))) short short8;
typedef __attribute__((ext_vector_type(4))) float f32x4;

#define S_   4096
#define HQ_  16
#define HKV_ 4
#define D_   64

static __device__ __forceinline__ unsigned short f2b(float f) {
    __hip_bfloat16 h = __float2bfloat16(f);
    return *reinterpret_cast<unsigned short*>(&h);
}
static __device__ __forceinline__ float b2f(unsigned short u) {
    union { unsigned int u; float f; } c;
    c.u = ((unsigned int)u) << 16;
    return c.f;
}

typedef __attribute__((address_space(1))) const unsigned int gas_u32;
typedef __attribute__((address_space(3))) unsigned int las_u32;
static __device__ __forceinline__ void gload16(const void* g, void* l) {
    __builtin_amdgcn_global_load_lds((gas_u32*)g, (las_u32*)l, 16, 0, 0);
}

// ---------------------------------------------------------------- prep (one kernel)
// z=0..3: weight transposes (Wq,Wk,Wv->WT; Wo->WoT), z=4: x->bf16, z=5: rope table.

__global__ __launch_bounds__(256) void k_prep(const float* __restrict__ Wq,
                                              const float* __restrict__ Wk,
                                              const float* __restrict__ Wv,
                                              const float* __restrict__ Wo,
                                              const float* __restrict__ x,
                                              unsigned short* __restrict__ WT,
                                              unsigned short* __restrict__ WoT,
                                              unsigned short* __restrict__ xb,
                                              float* __restrict__ cs) {
    const int z = blockIdx.z;
    const int t = threadIdx.x;
    if (z == 4) {                       // x -> bf16
        int flat = blockIdx.y * 32 + blockIdx.x;
#pragma unroll
        for (int ii = 0; ii < 4; ++ii) {
            int i = flat * 1024 + ii * 256 + t;
            float4 v = ((const float4*)x)[i];
            ushort4 o;
            o.x = f2b(v.x); o.y = f2b(v.y); o.z = f2b(v.z); o.w = f2b(v.w);
            ((ushort4*)xb)[i] = o;
        }
        return;
    }
    if (z == 5) {                       // rope table: 4096*32 entries
        int flat = blockIdx.y * 32 + blockIdx.x;
        if (flat >= 512) return;
        int i = flat * 256 + t;
        int s = i >> 5, jj = i & 31;
        float invf = exp2f(-(float)jj * (13.287712379549449f / 32.0f));
        float ang = (float)s * invf;
        ((float2*)cs)[i] = make_float2(cosf(ang), sinf(ang));
        return;
    }
    // weight transpose: out[N][K] bf16 = T(in[K][N] f32), K=1024
    const float* tin; unsigned short* tout; int N, gx;
    if (z == 0)      { tin = Wq; tout = WT;                 N = 1024; gx = 32; }
    else if (z == 1) { tin = Wk; tout = WT + 1024 * 1024;   N = 256;  gx = 8;  }
    else if (z == 2) { tin = Wv; tout = WT + 1280 * 1024;   N = 256;  gx = 8;  }
    else             { tin = Wo; tout = WoT;                N = 1024; gx = 32; }
    if ((int)blockIdx.x >= gx) return;
    __shared__ float tile[32][33];
    int tx = t & 31, ty = t >> 5;
    int n0 = blockIdx.x * 32, k0 = blockIdx.y * 32;
#pragma unroll
    for (int r = 0; r < 32; r += 8)
        tile[ty + r][tx] = tin[(size_t)(k0 + ty + r) * N + n0 + tx];
    __syncthreads();
#pragma unroll
    for (int r = 0; r < 32; r += 8)
        tout[(size_t)(n0 + ty + r) * 1024 + k0 + tx] = f2b(tile[tx][ty + r]);
}

// ---------------------------------------------------------------- QKV GEMM + fused RoPE/rearrange
// BM=128, BN=64 (one head per n-tile), BK=64, double-buffered 1-barrier
// pipeline. n-tiles 0..15: Q heads (RoPE + QS scale -> Qr), 16..19: K heads
// (RoPE -> Kr), 20..23: V heads -> Vp (kappa-permuted).

__global__ __launch_bounds__(256, 3)
void k_gemm_qkv(const unsigned short* __restrict__ A,   // xb [4096][1024]
                const unsigned short* __restrict__ BT,  // WT [1536][1024]
                const float* __restrict__ cs,
                unsigned short* __restrict__ Qr,
                unsigned short* __restrict__ Kr,
                unsigned short* __restrict__ Vp) {
    __shared__ unsigned short As[2][128 * 64];   // 2 x 16KB
    __shared__ unsigned short Bs[2][64 * 64];    // 2 x 8KB
    const int t = threadIdx.x;
    const int ntile = blockIdx.x;                 // 0..23
    const int n0 = ntile * 64;
    const int m0 = blockIdx.y * 128;
    const int w = t >> 6, lane = t & 63, lr = lane & 15, lg = lane >> 4;
    const int sr = lane >> 3, sch = (lane & 7) * 16;
    const int K = 1024;

    f32x4 acc[2][4];
#pragma unroll
    for (int m = 0; m < 2; ++m)
#pragma unroll
        for (int n = 0; n < 4; ++n) acc[m][n] = (f32x4){0.f, 0.f, 0.f, 0.f};

    auto stage = [&](int buf, int k0) {
#pragma unroll
        for (int c = 0; c < 4; ++c) {
            int r0 = w * 32 + c * 8;
            int r = r0 + sr;
            gload16((const char*)&A[(size_t)(m0 + r) * K + k0] + (sch ^ ((r & 7) << 4)),
                    (char*)&As[buf][0] + r0 * 128);
        }
#pragma unroll
        for (int c = 0; c < 2; ++c) {
            int r0 = w * 16 + c * 8;
            int r = r0 + sr;
            gload16((const char*)&BT[(size_t)(n0 + r) * K + k0] + (sch ^ ((r & 7) << 4)),
                    (char*)&Bs[buf][0] + r0 * 128);
        }
    };

    int cur = 0;
    stage(0, 0);
    __syncthreads();

    for (int k0 = 0; k0 < K; k0 += 64) {
        if (k0 + 64 < K) stage(cur ^ 1, k0 + 64);
        const char* AsB = (const char*)&As[cur][0];
        const char* BsB = (const char*)&Bs[cur][0];
        __builtin_amdgcn_s_setprio(1);
#pragma unroll
        for (int kk = 0; kk < 2; ++kk) {
            short8 af[2], bf[4];
#pragma unroll
            for (int m = 0; m < 2; ++m) {
                int arow = w * 32 + m * 16 + lr;
                af[m] = *(const short8*)(AsB + arow * 128 +
                                         ((kk * 64 + lg * 16) ^ ((arow & 7) << 4)));
            }
#pragma unroll
            for (int n = 0; n < 4; ++n) {
                int brow = n * 16 + lr;
                bf[n] = *(const short8*)(BsB + brow * 128 +
                                         ((kk * 64 + lg * 16) ^ ((brow & 7) << 4)));
            }
#pragma unroll
            for (int m = 0; m < 2; ++m)
#pragma unroll
                for (int n = 0; n < 4; ++n)
                    acc[m][n] = __builtin_amdgcn_mfma_f32_16x16x32_bf16(af[m], bf[n], acc[m][n], 0, 0, 0);
        }
        __builtin_amdgcn_s_setprio(0);
        __syncthreads();                          // reads done + prefetch landed
        cur ^= 1;
    }

    if (ntile < 20) {
        // RoPE epilogue. d pairs (d, d+32) = (acc[m][nt], acc[m][nt+2]), nt=0,1.
        const float QS = (ntile < 16) ? 0.125f * 1.44269504088896340736f : 1.0f;
        unsigned short* dst = (ntile < 16) ? (Qr + (size_t)ntile * (S_ * D_))
                                           : (Kr + (size_t)(ntile - 16) * (S_ * D_));
#pragma unroll
        for (int m = 0; m < 2; ++m)
#pragma unroll
            for (int rr = 0; rr < 4; ++rr) {
                int s = m0 + w * 32 + m * 16 + lg * 4 + rr;
                const float2* csr = (const float2*)cs + s * 32;
                float2 c0 = csr[lr];
                float2 c1 = csr[16 + lr];
                float t1 = acc[m][0][rr], t2 = acc[m][2][rr];
                dst[(size_t)s * 64 + lr]      = f2b((t1 * c0.x - t2 * c0.y) * QS);
                dst[(size_t)s * 64 + 32 + lr] = f2b((t2 * c0.x + t1 * c0.y) * QS);
                t1 = acc[m][1][rr]; t2 = acc[m][3][rr];
                dst[(size_t)s * 64 + 16 + lr] = f2b((t1 * c1.x - t2 * c1.y) * QS);
                dst[(size_t)s * 64 + 48 + lr] = f2b((t2 * c1.x + t1 * c1.y) * QS);
            }
    } else {
        int h2 = ntile - 20;
        unsigned short* dst = Vp + (size_t)h2 * (D_ * S_);
        // permuted store: s = m0 + w*32 + m*16 + lg*4 + rr  maps to
        // pos = m0 + (w>>1)*64 + (w&1)*32 + lg*8 + m*4 + rr  (rr contiguous)
#pragma unroll
        for (int m = 0; m < 2; ++m)
#pragma unroll
            for (int n = 0; n < 4; ++n) {
                int d = n * 16 + lr;
                int pos = m0 + (w >> 1) * 64 + (w & 1) * 32 + lg * 8 + m * 4;
                ushort4 o;
                o.x = f2b(acc[m][n][0]); o.y = f2b(acc[m][n][1]);
                o.z = f2b(acc[m][n][2]); o.w = f2b(acc[m][n][3]);
                *(ushort4*)&dst[(size_t)d * S_ + pos] = o;
            }
    }
}

// ---------------------------------------------------------------- Wo GEMM
// BM=128, BN=64, BK=64, double-buffered 1-barrier pipeline, f32 out.

__global__ __launch_bounds__(256, 3)
void k_gemm_o(const unsigned short* __restrict__ A,   // O [4096][1024]
              const unsigned short* __restrict__ BT,  // WoT [1024][1024]
              float* __restrict__ out) {
    __shared__ unsigned short As[2][128 * 64];
    __shared__ unsigned short Bs[2][64 * 64];
    const int t = threadIdx.x;
    const int n0 = blockIdx.x * 64;
    const int m0 = blockIdx.y * 128;
    const int w = t >> 6, lane = t & 63, lr = lane & 15, lg = lane >> 4;
    const int sr = lane >> 3, sch = (lane & 7) * 16;
    const int K = 1024;

    f32x4 acc[2][4];
#pragma unroll
    for (int m = 0; m < 2; ++m)
#pragma unroll
        for (int n = 0; n < 4; ++n) acc[m][n] = (f32x4){0.f, 0.f, 0.f, 0.f};

    auto stage = [&](int buf, int k0) {
#pragma unroll
        for (int c = 0; c < 4; ++c) {
            int r0 = w * 32 + c * 8;
            int r = r0 + sr;
            gload16((const char*)&A[(size_t)(m0 + r) * K + k0] + (sch ^ ((r & 7) << 4)),
                    (char*)&As[buf][0] + r0 * 128);
        }
#pragma unroll
        for (int c = 0; c < 2; ++c) {
            int r0 = w * 16 + c * 8;
            int r = r0 + sr;
            gload16((const char*)&BT[(size_t)(n0 + r) * K + k0] + (sch ^ ((r & 7) << 4)),
                    (char*)&Bs[buf][0] + r0 * 128);
        }
    };

    int cur = 0;
    stage(0, 0);
    __syncthreads();

    for (int k0 = 0; k0 < K; k0 += 64) {
        if (k0 + 64 < K) stage(cur ^ 1, k0 + 64);
        const char* AsB = (const char*)&As[cur][0];
        const char* BsB = (const char*)&Bs[cur][0];
        __builtin_amdgcn_s_setprio(1);
#pragma unroll
        for (int kk = 0; kk < 2; ++kk) {
            short8 af[2], bf[4];
#pragma unroll
            for (int m = 0; m < 2; ++m) {
                int arow = w * 32 + m * 16 + lr;
                af[m] = *(const short8*)(AsB + arow * 128 +
                                         ((kk * 64 + lg * 16) ^ ((arow & 7) << 4)));
            }
#pragma unroll
            for (int n = 0; n < 4; ++n) {
                int brow = n * 16 + lr;
                bf[n] = *(const short8*)(BsB + brow * 128 +
                                         ((kk * 64 + lg * 16) ^ ((brow & 7) << 4)));
            }
#pragma unroll
            for (int m = 0; m < 2; ++m)
#pragma unroll
                for (int n = 0; n < 4; ++n)
                    acc[m][n] = __builtin_amdgcn_mfma_f32_16x16x32_bf16(af[m], bf[n], acc[m][n], 0, 0, 0);
        }
        __builtin_amdgcn_s_setprio(0);
        __syncthreads();
        cur ^= 1;
    }
#pragma unroll
    for (int m = 0; m < 2; ++m)
#pragma unroll
        for (int n = 0; n < 4; ++n)
#pragma unroll
            for (int rr = 0; rr < 4; ++rr) {
                int row = m0 + w * 32 + m * 16 + lg * 4 + rr;
                int col = n0 + n * 16 + lr;
                out[(size_t)row * 1024 + col] = acc[m][n][rr];
            }
}

// ---------------------------------------------------------------- flash attention
// Round-9/10 inner body (68 us, 0 conflicts) at 5 blocks/CU:
// Grid (64,16,2) = 2048 blocks, heavy-first (qb = 63-bx) so the scheduler
// LPT-backfills. LDS 32KB x 5 = 160KB exactly; __launch_bounds__(256,5).
// Block (bx,h,j): q-block of 64 rows (4 waves x 16); kv-tiles kb = j, j+2,
// ..., qb (2-way K-split). Register-direct PV via permuted Vp (single b128
// B-frag, K-read pattern). exp2-direct softmax; per-lane sums reduced once.

__global__ __launch_bounds__(256, 5)
void k_attn(const unsigned short* __restrict__ Qr, // [HQ][S][D]
            const unsigned short* __restrict__ Kr, // [HKV][S][D]
            const unsigned short* __restrict__ Vp, // [HKV][D][S-permuted]
            unsigned short* __restrict__ Pacc,     // [2][64][16][64][64] bf16
            float* __restrict__ Psv) {             // [2][64][16][64]
    __shared__ unsigned short Ks[2][64 * 64];    // [kv][d], src-swizzled
    __shared__ unsigned short Vs[2][64 * 64];    // [d][kperm], src-swizzled

    const int t = threadIdx.x;
    const int qb = 63 - (int)blockIdx.x;         // heavy first (LPT backfill)
    const int h = blockIdx.y;
    const int j = blockIdx.z;                    // K-split parity
    const int kvh = h >> 2;
    const int w = t >> 6, lane = t & 63, lr = lane & 15, lg = lane >> 4;

    const unsigned short* Qh = Qr + (size_t)h * (S_ * D_);
    const unsigned short* Kh = Kr + (size_t)kvh * (S_ * D_);
    const unsigned short* Vh = Vp + (size_t)kvh * (D_ * S_);

    const int xw = (lr & 7) << 4;
    const int sr = lane >> 3, sch = (lane & 7) * 16;
    const int r0a = w * 16, r0b = w * 16 + 8;

    const int tend = qb + 1;                     // kv tiles: 0..qb
    const int qi = qb * 64 + w * 16 + lr;        // this lane's q-row

    const char* kp[2];
    const char* vp[2];
    {
        int ra = r0a + sr, rb = r0b + sr;
        kp[0] = (const char*)(Kh + (size_t)(j * 64 + ra) * 64) + (sch ^ ((ra & 7) << 4));
        kp[1] = (const char*)(Kh + (size_t)(j * 64 + rb) * 64) + (sch ^ ((rb & 7) << 4));
        vp[0] = (const char*)(Vh + (size_t)ra * S_ + j * 64) + (sch ^ ((ra & 7) << 4));
        vp[1] = (const char*)(Vh + (size_t)rb * S_ + j * 64) + (sch ^ ((rb & 7) << 4));
    }
    auto stage = [&](int buf) {
        gload16(kp[0], (char*)&Ks[buf][0] + r0a * 128);
        gload16(kp[1], (char*)&Ks[buf][0] + r0b * 128);
        gload16(vp[0], (char*)&Vs[buf][0] + r0a * 128);
        gload16(vp[1], (char*)&Vs[buf][0] + r0b * 128);
        kp[0] += 16384; kp[1] += 16384;      // +128 keys (2 tiles)
        vp[0] += 256;   vp[1] += 256;        // +128 key-positions
    };

    short8 aq[2];
    {
        int qrow = qb * 64 + w * 16 + lr;
        aq[0] = *(const short8*)&Qh[(size_t)qrow * 64 + lg * 8];
        aq[1] = *(const short8*)&Qh[(size_t)qrow * 64 + 32 + lg * 8];
    }
    float svl = 0.f;
    f32x4 acc_o[4];
#pragma unroll
    for (int i = 0; i < 4; ++i) acc_o[i] = (f32x4){0.f, 0.f, 0.f, 0.f};

    int cur = 0;
    stage(0);
    __syncthreads();

    for (int kb = j; kb < tend; kb += 2) {
        if (kb + 2 < tend) stage(cur ^ 1);

        // ---- S^T = K Q^T: s[nt] = P[k=nt*16+lg*4+r][q=lr]
        f32x4 s[4];
#pragma unroll
        for (int i = 0; i < 4; ++i) s[i] = (f32x4){0.f, 0.f, 0.f, 0.f};
        const char* KsB = (const char*)&Ks[cur][0];
        __builtin_amdgcn_s_setprio(1);
#pragma unroll
        for (int kk = 0; kk < 2; ++kk)
#pragma unroll
            for (int nt = 0; nt < 4; ++nt) {
                short8 kf = *(const short8*)(KsB + (nt * 16 + lr) * 128 + ((kk * 64 + lg * 16) ^ xw));
                s[nt] = __builtin_amdgcn_mfma_f32_16x16x32_bf16(kf, aq[kk], s[nt], 0, 0, 0);
            }
        __builtin_amdgcn_s_setprio(0);

        // ---- causal mask on diagonal tile
        if (kb == qb) {
            int kbase = kb * 64 + lg * 4;
#pragma unroll
            for (int nt = 0; nt < 4; ++nt)
#pragma unroll
                for (int rr = 0; rr < 4; ++rr)
                    if (kbase + nt * 16 + rr > qi) s[nt][rr] = -INFINITY;
        }

        // ---- p = exp2(s), pack in-lane (A-frag words, kappa order), sum
        unsigned int wd[8];
#pragma unroll
        for (int nt = 0; nt < 4; ++nt) {
            float p0 = exp2f(s[nt][0]), p1 = exp2f(s[nt][1]);
            float p2 = exp2f(s[nt][2]), p3 = exp2f(s[nt][3]);
            svl += (p0 + p1) + (p2 + p3);
            asm("v_cvt_pk_bf16_f32 %0, %1, %2" : "=v"(wd[nt * 2])     : "v"(p0), "v"(p1));
            asm("v_cvt_pk_bf16_f32 %0, %1, %2" : "=v"(wd[nt * 2 + 1]) : "v"(p2), "v"(p3));
        }

        // ---- O += P V  (kappa-ordered contraction; single b128 B-frag)
        const char* VsB = (const char*)&Vs[cur][0];
        __builtin_amdgcn_s_setprio(1);
#pragma unroll
        for (int kk = 0; kk < 2; ++kk) {
            union { unsigned int u[4]; short8 s8; } pa;
            pa.u[0] = wd[4 * kk + 0]; pa.u[1] = wd[4 * kk + 1];
            pa.u[2] = wd[4 * kk + 2]; pa.u[3] = wd[4 * kk + 3];
#pragma unroll
            for (int nt = 0; nt < 4; ++nt) {
                short8 vb = *(const short8*)(VsB + (nt * 16 + lr) * 128 + ((kk * 64 + lg * 16) ^ xw));
                acc_o[nt] = __builtin_amdgcn_mfma_f32_16x16x32_bf16(pa.s8, vb, acc_o[nt], 0, 0, 0);
            }
        }
        __builtin_amdgcn_s_setprio(0);

        __syncthreads();                     // buf free + prefetch landed
        cur ^= 1;
    }

    // ---- epilogue: reduce row sum once, write partials
    svl += __shfl_xor(svl, 16);
    svl += __shfl_xor(svl, 32);
    const int u = ((j * 64 + qb) * 16 + h);
    if (lg == 0) Psv[u * 64 + w * 16 + lr] = svl;
    unsigned short* Pb = Pacc + (size_t)u * 4096;
#pragma unroll
    for (int nt = 0; nt < 4; ++nt) {
        int rr = w * 16 + lg * 4;
        int col = nt * 16 + lr;
        Pb[(rr + 0) * 64 + col] = f2b(acc_o[nt][0]);
        Pb[(rr + 1) * 64 + col] = f2b(acc_o[nt][1]);
        Pb[(rr + 2) * 64 + col] = f2b(acc_o[nt][2]);
        Pb[(rr + 3) * 64 + col] = f2b(acc_o[nt][3]);
    }
}

// ---------------------------------------------------------------- combine splits

__global__ __launch_bounds__(256) void k_combine(const unsigned short* __restrict__ Pacc,
                                                 const float* __restrict__ Psv,
                                                 unsigned short* __restrict__ O) {
    const int qb = blockIdx.x, h = blockIdx.y;
    const int t = threadIdx.x;
    const int r = t >> 2, db = (t & 3) * 16;
    const int u0 = (qb * 16 + h);
    const int u1 = ((64 + qb) * 16 + h);
    float sa = Psv[u0 * 64 + r], sb = Psv[u1 * 64 + r];
    float inv = 1.f / (sa + sb);
    const unsigned short* A_ = Pacc + (size_t)u0 * 4096 + r * 64 + db;
    const unsigned short* B_ = Pacc + (size_t)u1 * 4096 + r * 64 + db;
    unsigned short* Op = O + (size_t)(qb * 64 + r) * 1024 + h * 64 + db;
#pragma unroll
    for (int halfv = 0; halfv < 2; ++halfv) {
        short8 va = *(const short8*)(A_ + halfv * 8);
        short8 vb = *(const short8*)(B_ + halfv * 8);
        short8 o;
#pragma unroll
        for (int i = 0; i < 8; ++i)
            o[i] = (short)f2b((b2f((unsigned short)va[i]) + b2f((unsigned short)vb[i])) * inv);
        *(short8*)(Op + halfv * 8) = o;
    }
}

// ---------------------------------------------------------------- launch

extern "C" void kernel_launch(void* const* d_in, const int* in_sizes, int n_in,
                              void* d_out, int out_size, void* d_ws, size_t ws_size,
                              hipStream_t stream) {
    const float* x  = (const float*)d_in[0];
    const float* Wq = (const float*)d_in[1];
    const float* Wk = (const float*)d_in[2];
    const float* Wv = (const float*)d_in[3];
    const float* Wo = (const float*)d_in[4];
    float* out = (float*)d_out;
    char* ws = (char*)d_ws;

    unsigned short* WT  = (unsigned short*)(ws + 0);          // [1536][1024] bf16, 3MB
    unsigned short* WoT = (unsigned short*)(ws + 3145728);    // [1024][1024], 2MB
    unsigned short* Qr  = (unsigned short*)(ws + 5242880);    // [16][4096][64], 8MB
    unsigned short* Kr  = (unsigned short*)(ws + 13631488);   // [4][4096][64], 2MB
    unsigned short* Vp  = (unsigned short*)(ws + 15728640);   // [4][64][4096] permuted, 2MB
    unsigned short* O   = (unsigned short*)(ws + 17825792);   // [4096][1024], 8MB
    float* cs           = (float*)(ws + 26214400);            // [4096][32] x {cos,sin}, 1MB
    unsigned short* xb  = (unsigned short*)(ws + 27262976);   // [4096][1024], 8MB (dies after QKV)
    // attn partials overlay xb (dead by then):
    unsigned short* Pacc = (unsigned short*)(ws + 27262976);  // [2][64][16][64][64], 16.78MB
    float* Psv           = (float*)(ws + 44040192);           // [2][64][16][64], 0.5MB

    k_prep<<<dim3(32, 32, 6), 256, 0, stream>>>(Wq, Wk, Wv, Wo, x, WT, WoT, xb, cs);
    k_gemm_qkv<<<dim3(24, 32), 256, 0, stream>>>(xb, WT, cs, Qr, Kr, Vp);
    k_attn<<<dim3(64, 16, 2), 256, 0, stream>>>(Qr, Kr, Vp, Pacc, Psv);
    k_combine<<<dim3(64, 16), 256, 0, stream>>>(Pacc, Psv, O);
    k_gemm_o<<<dim3(16, 32), 256, 0, stream>>>(O, WoT, out);
}

// Round 13
// 127.979 us; speedup vs baseline: 1.0915x; 1.0915x over previous
//
#include <hip/hip_runtime.h>
#include <hip/hip_bf16.h>
#include <math.h>

typedef __attribute__((ext_vector_type(8))) short short8;
typedef __attribute__((ext_vector_type(4))) float f32x4;

#define S_   4096
#define HQ_  16
#define HKV_ 4
#define D_   64

static __device__ __forceinline__ unsigned short f2b(float f) {
    __hip_bfloat16 h = __float2bfloat16(f);
    return *reinterpret_cast<unsigned short*>(&h);
}
static __device__ __forceinline__ float b2f(unsigned short u) {
    union { unsigned int u; float f; } c;
    c.u = ((unsigned int)u) << 16;
    return c.f;
}

typedef __attribute__((address_space(1))) const unsigned int gas_u32;
typedef __attribute__((address_space(3))) unsigned int las_u32;
static __device__ __forceinline__ void gload16(const void* g, void* l) {
    __builtin_amdgcn_global_load_lds((gas_u32*)g, (las_u32*)l, 16, 0, 0);
}

// ---------------------------------------------------------------- prep (one kernel)
// z=0..3: weight transposes (Wq,Wk,Wv->WT; Wo->WoT), z=4: x->bf16, z=5: rope table.

__global__ __launch_bounds__(256) void k_prep(const float* __restrict__ Wq,
                                              const float* __restrict__ Wk,
                                              const float* __restrict__ Wv,
                                              const float* __restrict__ Wo,
                                              const float* __restrict__ x,
                                              unsigned short* __restrict__ WT,
                                              unsigned short* __restrict__ WoT,
                                              unsigned short* __restrict__ xb,
                                              float* __restrict__ cs) {
    const int z = blockIdx.z;
    const int t = threadIdx.x;
    if (z == 4) {                       // x -> bf16
        int flat = blockIdx.y * 32 + blockIdx.x;
#pragma unroll
        for (int ii = 0; ii < 4; ++ii) {
            int i = flat * 1024 + ii * 256 + t;
            float4 v = ((const float4*)x)[i];
            ushort4 o;
            o.x = f2b(v.x); o.y = f2b(v.y); o.z = f2b(v.z); o.w = f2b(v.w);
            ((ushort4*)xb)[i] = o;
        }
        return;
    }
    if (z == 5) {                       // rope table: 4096*32 entries
        int flat = blockIdx.y * 32 + blockIdx.x;
        if (flat >= 512) return;
        int i = flat * 256 + t;
        int s = i >> 5, jj = i & 31;
        float invf = exp2f(-(float)jj * (13.287712379549449f / 32.0f));
        float ang = (float)s * invf;
        ((float2*)cs)[i] = make_float2(cosf(ang), sinf(ang));
        return;
    }
    // weight transpose: out[N][K] bf16 = T(in[K][N] f32), K=1024
    const float* tin; unsigned short* tout; int N, gx;
    if (z == 0)      { tin = Wq; tout = WT;                 N = 1024; gx = 32; }
    else if (z == 1) { tin = Wk; tout = WT + 1024 * 1024;   N = 256;  gx = 8;  }
    else if (z == 2) { tin = Wv; tout = WT + 1280 * 1024;   N = 256;  gx = 8;  }
    else             { tin = Wo; tout = WoT;                N = 1024; gx = 32; }
    if ((int)blockIdx.x >= gx) return;
    __shared__ float tile[32][33];
    int tx = t & 31, ty = t >> 5;
    int n0 = blockIdx.x * 32, k0 = blockIdx.y * 32;
#pragma unroll
    for (int r = 0; r < 32; r += 8)
        tile[ty + r][tx] = tin[(size_t)(k0 + ty + r) * N + n0 + tx];
    __syncthreads();
#pragma unroll
    for (int r = 0; r < 32; r += 8)
        tout[(size_t)(n0 + ty + r) * 1024 + k0 + tx] = f2b(tile[tx][ty + r]);
}

// ---------------------------------------------------------------- QKV GEMM + fused RoPE/rearrange
// BM=128, BN=64 (one head per n-tile), BK=64, double-buffered 1-barrier
// pipeline. n-tiles 0..15: Q heads (RoPE + QS scale -> Qr), 16..19: K heads
// (RoPE -> Kr), 20..23: V heads -> Vp (kappa-permuted).

__global__ __launch_bounds__(256, 3)
void k_gemm_qkv(const unsigned short* __restrict__ A,   // xb [4096][1024]
                const unsigned short* __restrict__ BT,  // WT [1536][1024]
                const float* __restrict__ cs,
                unsigned short* __restrict__ Qr,
                unsigned short* __restrict__ Kr,
                unsigned short* __restrict__ Vp) {
    __shared__ unsigned short As[2][128 * 64];   // 2 x 16KB
    __shared__ unsigned short Bs[2][64 * 64];    // 2 x 8KB
    const int t = threadIdx.x;
    const int ntile = blockIdx.x;                 // 0..23
    const int n0 = ntile * 64;
    const int m0 = blockIdx.y * 128;
    const int w = t >> 6, lane = t & 63, lr = lane & 15, lg = lane >> 4;
    const int sr = lane >> 3, sch = (lane & 7) * 16;
    const int K = 1024;

    f32x4 acc[2][4];
#pragma unroll
    for (int m = 0; m < 2; ++m)
#pragma unroll
        for (int n = 0; n < 4; ++n) acc[m][n] = (f32x4){0.f, 0.f, 0.f, 0.f};

    auto stage = [&](int buf, int k0) {
#pragma unroll
        for (int c = 0; c < 4; ++c) {
            int r0 = w * 32 + c * 8;
            int r = r0 + sr;
            gload16((const char*)&A[(size_t)(m0 + r) * K + k0] + (sch ^ ((r & 7) << 4)),
                    (char*)&As[buf][0] + r0 * 128);
        }
#pragma unroll
        for (int c = 0; c < 2; ++c) {
            int r0 = w * 16 + c * 8;
            int r = r0 + sr;
            gload16((const char*)&BT[(size_t)(n0 + r) * K + k0] + (sch ^ ((r & 7) << 4)),
                    (char*)&Bs[buf][0] + r0 * 128);
        }
    };

    int cur = 0;
    stage(0, 0);
    __syncthreads();

    for (int k0 = 0; k0 < K; k0 += 64) {
        if (k0 + 64 < K) stage(cur ^ 1, k0 + 64);
        const char* AsB = (const char*)&As[cur][0];
        const char* BsB = (const char*)&Bs[cur][0];
        __builtin_amdgcn_s_setprio(1);
#pragma unroll
        for (int kk = 0; kk < 2; ++kk) {
            short8 af[2], bf[4];
#pragma unroll
            for (int m = 0; m < 2; ++m) {
                int arow = w * 32 + m * 16 + lr;
                af[m] = *(const short8*)(AsB + arow * 128 +
                                         ((kk * 64 + lg * 16) ^ ((arow & 7) << 4)));
            }
#pragma unroll
            for (int n = 0; n < 4; ++n) {
                int brow = n * 16 + lr;
                bf[n] = *(const short8*)(BsB + brow * 128 +
                                         ((kk * 64 + lg * 16) ^ ((brow & 7) << 4)));
            }
#pragma unroll
            for (int m = 0; m < 2; ++m)
#pragma unroll
                for (int n = 0; n < 4; ++n)
                    acc[m][n] = __builtin_amdgcn_mfma_f32_16x16x32_bf16(af[m], bf[n], acc[m][n], 0, 0, 0);
        }
        __builtin_amdgcn_s_setprio(0);
        __syncthreads();                          // reads done + prefetch landed
        cur ^= 1;
    }

    if (ntile < 20) {
        // RoPE epilogue. d pairs (d, d+32) = (acc[m][nt], acc[m][nt+2]), nt=0,1.
        const float QS = (ntile < 16) ? 0.125f * 1.44269504088896340736f : 1.0f;
        unsigned short* dst = (ntile < 16) ? (Qr + (size_t)ntile * (S_ * D_))
                                           : (Kr + (size_t)(ntile - 16) * (S_ * D_));
#pragma unroll
        for (int m = 0; m < 2; ++m)
#pragma unroll
            for (int rr = 0; rr < 4; ++rr) {
                int s = m0 + w * 32 + m * 16 + lg * 4 + rr;
                const float2* csr = (const float2*)cs + s * 32;
                float2 c0 = csr[lr];
                float2 c1 = csr[16 + lr];
                float t1 = acc[m][0][rr], t2 = acc[m][2][rr];
                dst[(size_t)s * 64 + lr]      = f2b((t1 * c0.x - t2 * c0.y) * QS);
                dst[(size_t)s * 64 + 32 + lr] = f2b((t2 * c0.x + t1 * c0.y) * QS);
                t1 = acc[m][1][rr]; t2 = acc[m][3][rr];
                dst[(size_t)s * 64 + 16 + lr] = f2b((t1 * c1.x - t2 * c1.y) * QS);
                dst[(size_t)s * 64 + 48 + lr] = f2b((t2 * c1.x + t1 * c1.y) * QS);
            }
    } else {
        int h2 = ntile - 20;
        unsigned short* dst = Vp + (size_t)h2 * (D_ * S_);
        // permuted store: s = m0 + w*32 + m*16 + lg*4 + rr  maps to
        // pos = m0 + (w>>1)*64 + (w&1)*32 + lg*8 + m*4 + rr  (rr contiguous)
#pragma unroll
        for (int m = 0; m < 2; ++m)
#pragma unroll
            for (int n = 0; n < 4; ++n) {
                int d = n * 16 + lr;
                int pos = m0 + (w >> 1) * 64 + (w & 1) * 32 + lg * 8 + m * 4;
                ushort4 o;
                o.x = f2b(acc[m][n][0]); o.y = f2b(acc[m][n][1]);
                o.z = f2b(acc[m][n][2]); o.w = f2b(acc[m][n][3]);
                *(ushort4*)&dst[(size_t)d * S_ + pos] = o;
            }
    }
}

// ---------------------------------------------------------------- flash attention
// (exact round-10 structure: 68 us, 0 bank conflicts, occ ~31%)
// Grid (32,16,2) = 1024 uniform blocks (4 blocks/CU, LDS 32KB). Block (p,h,j)
// handles q-blocks {63-p, p} (64 rows, 4 waves x 16 rows) -- triangle pairing.
// kv-tiles kb = j, j+2, ... (2-way K-split). Register-direct PV via permuted
// Vp (single b128 B-frag, K-read pattern). exp2-direct softmax.

__global__ __launch_bounds__(256, 4)
void k_attn(const unsigned short* __restrict__ Qr, // [HQ][S][D]
            const unsigned short* __restrict__ Kr, // [HKV][S][D]
            const unsigned short* __restrict__ Vp, // [HKV][D][S-permuted]
            unsigned short* __restrict__ Pacc,     // [2][64][16][64][64] bf16
            float* __restrict__ Psv) {             // [2][64][16][64]
    __shared__ unsigned short Ks[2][64 * 64];    // [kv][d], src-swizzled
    __shared__ unsigned short Vs[2][64 * 64];    // [d][kperm], src-swizzled

    const int t = threadIdx.x;
    const int p = blockIdx.x;                    // 0..31
    const int h = blockIdx.y;
    const int j = blockIdx.z;                    // K-split parity
    const int kvh = h >> 2;
    const int w = t >> 6, lane = t & 63, lr = lane & 15, lg = lane >> 4;

    const unsigned short* Qh = Qr + (size_t)h * (S_ * D_);
    const unsigned short* Kh = Kr + (size_t)kvh * (S_ * D_);
    const unsigned short* Vh = Vp + (size_t)kvh * (D_ * S_);

    const int xw = (lr & 7) << 4;
    const int sr = lane >> 3, sch = (lane & 7) * 16;
    const int r0a = w * 16, r0b = w * 16 + 8;

#pragma unroll 1
    for (int half = 0; half < 2; ++half) {
        const int qb = half ? p : (63 - p);
        const int tend = qb + 1;                 // kv tiles: 0..qb
        const int qi = qb * 64 + w * 16 + lr;    // this lane's q-row

        const char* kp[2];
        const char* vp[2];
        {
            int ra = r0a + sr, rb = r0b + sr;
            kp[0] = (const char*)(Kh + (size_t)(j * 64 + ra) * 64) + (sch ^ ((ra & 7) << 4));
            kp[1] = (const char*)(Kh + (size_t)(j * 64 + rb) * 64) + (sch ^ ((rb & 7) << 4));
            vp[0] = (const char*)(Vh + (size_t)ra * S_ + j * 64) + (sch ^ ((ra & 7) << 4));
            vp[1] = (const char*)(Vh + (size_t)rb * S_ + j * 64) + (sch ^ ((rb & 7) << 4));
        }
        auto stage = [&](int buf) {
            gload16(kp[0], (char*)&Ks[buf][0] + r0a * 128);
            gload16(kp[1], (char*)&Ks[buf][0] + r0b * 128);
            gload16(vp[0], (char*)&Vs[buf][0] + r0a * 128);
            gload16(vp[1], (char*)&Vs[buf][0] + r0b * 128);
            kp[0] += 16384; kp[1] += 16384;      // +128 keys (2 tiles)
            vp[0] += 256;   vp[1] += 256;        // +128 key-positions
        };

        short8 aq[2];
        {
            int qrow = qb * 64 + w * 16 + lr;
            aq[0] = *(const short8*)&Qh[(size_t)qrow * 64 + lg * 8];
            aq[1] = *(const short8*)&Qh[(size_t)qrow * 64 + 32 + lg * 8];
        }
        float svl = 0.f;
        f32x4 acc_o[4];
#pragma unroll
        for (int i = 0; i < 4; ++i) acc_o[i] = (f32x4){0.f, 0.f, 0.f, 0.f};

        int cur = 0;
        stage(0);
        __syncthreads();

        for (int kb = j; kb < tend; kb += 2) {
            if (kb + 2 < tend) stage(cur ^ 1);

            // ---- S^T = K Q^T: s[nt] = P[k=nt*16+lg*4+r][q=lr]
            f32x4 s[4];
#pragma unroll
            for (int i = 0; i < 4; ++i) s[i] = (f32x4){0.f, 0.f, 0.f, 0.f};
            const char* KsB = (const char*)&Ks[cur][0];
            __builtin_amdgcn_s_setprio(1);
#pragma unroll
            for (int kk = 0; kk < 2; ++kk)
#pragma unroll
                for (int nt = 0; nt < 4; ++nt) {
                    short8 kf = *(const short8*)(KsB + (nt * 16 + lr) * 128 + ((kk * 64 + lg * 16) ^ xw));
                    s[nt] = __builtin_amdgcn_mfma_f32_16x16x32_bf16(kf, aq[kk], s[nt], 0, 0, 0);
                }
            __builtin_amdgcn_s_setprio(0);

            // ---- causal mask on diagonal tile
            if (kb == qb) {
                int kbase = kb * 64 + lg * 4;
#pragma unroll
                for (int nt = 0; nt < 4; ++nt)
#pragma unroll
                    for (int rr = 0; rr < 4; ++rr)
                        if (kbase + nt * 16 + rr > qi) s[nt][rr] = -INFINITY;
            }

            // ---- p = exp2(s), pack in-lane (A-frag words, kappa order), sum
            unsigned int wd[8];
#pragma unroll
            for (int nt = 0; nt < 4; ++nt) {
                float p0 = exp2f(s[nt][0]), p1 = exp2f(s[nt][1]);
                float p2 = exp2f(s[nt][2]), p3 = exp2f(s[nt][3]);
                svl += (p0 + p1) + (p2 + p3);
                asm("v_cvt_pk_bf16_f32 %0, %1, %2" : "=v"(wd[nt * 2])     : "v"(p0), "v"(p1));
                asm("v_cvt_pk_bf16_f32 %0, %1, %2" : "=v"(wd[nt * 2 + 1]) : "v"(p2), "v"(p3));
            }

            // ---- O += P V  (kappa-ordered contraction; single b128 B-frag)
            const char* VsB = (const char*)&Vs[cur][0];
            __builtin_amdgcn_s_setprio(1);
#pragma unroll
            for (int kk = 0; kk < 2; ++kk) {
                union { unsigned int u[4]; short8 s8; } pa;
                pa.u[0] = wd[4 * kk + 0]; pa.u[1] = wd[4 * kk + 1];
                pa.u[2] = wd[4 * kk + 2]; pa.u[3] = wd[4 * kk + 3];
#pragma unroll
                for (int nt = 0; nt < 4; ++nt) {
                    short8 vb = *(const short8*)(VsB + (nt * 16 + lr) * 128 + ((kk * 64 + lg * 16) ^ xw));
                    acc_o[nt] = __builtin_amdgcn_mfma_f32_16x16x32_bf16(pa.s8, vb, acc_o[nt], 0, 0, 0);
                }
            }
            __builtin_amdgcn_s_setprio(0);

            __syncthreads();                     // buf free + prefetch landed
            cur ^= 1;
        }

        // ---- epilogue: reduce row sum once, write partials
        svl += __shfl_xor(svl, 16);
        svl += __shfl_xor(svl, 32);
        const int u = ((j * 64 + qb) * 16 + h);
        if (lg == 0) Psv[u * 64 + w * 16 + lr] = svl;
        unsigned short* Pb = Pacc + (size_t)u * 4096;
#pragma unroll
        for (int nt = 0; nt < 4; ++nt) {
            int rr = w * 16 + lg * 4;
            int col = nt * 16 + lr;
            Pb[(rr + 0) * 64 + col] = f2b(acc_o[nt][0]);
            Pb[(rr + 1) * 64 + col] = f2b(acc_o[nt][1]);
            Pb[(rr + 2) * 64 + col] = f2b(acc_o[nt][2]);
            Pb[(rr + 3) * 64 + col] = f2b(acc_o[nt][3]);
        }
    }
}

// ---------------------------------------------------------------- Wo GEMM with fused combine
// out = ((Pacc[j=0] + Pacc[j=1]) * inv[s,h]) @ WoT.  BM=128, BN=64, BK=64;
// K-step ks covers exactly head h=ks, so A-tile is built in registers from
// the two split partials with the per-(s,h) normalization folded in (T14
// split: issue loads for step t+1, compute step t, convert+ds_write after).
// A writes use the proven XOR-swizzled layout; B stays global_load_lds.

__global__ __launch_bounds__(256, 3)
void k_gemm_o(const unsigned short* __restrict__ Pacc,  // [2][64][16][64][64] bf16
              const float* __restrict__ Psv,            // [2][64][16][64]
              const unsigned short* __restrict__ BT,    // WoT [1024][1024]
              float* __restrict__ out) {
    __shared__ unsigned short As[2][128 * 64];
    __shared__ unsigned short Bs[2][64 * 64];
    const int t = threadIdx.x;
    const int n0 = blockIdx.x * 64;
    const int m0 = blockIdx.y * 128;
    const int w = t >> 6, lane = t & 63, lr = lane & 15, lg = lane >> 4;
    const int sr = lane >> 3, sch = (lane & 7) * 16;

    f32x4 acc[2][4];
#pragma unroll
    for (int m = 0; m < 2; ++m)
#pragma unroll
        for (int n = 0; n < 4; ++n) acc[m][n] = (f32x4){0.f, 0.f, 0.f, 0.f};

    int4 a0[4], a1[4];
    float svs[4];

    auto issueA = [&](int ks) {                  // global loads for A (no LDS yet)
#pragma unroll
        for (int c = 0; c < 4; ++c) {
            int r = w * 32 + c * 8 + sr;
            int s = m0 + r;
            int row6 = s & 63, qbb = s >> 6;
            int u0 = qbb * 16 + ks;
            int u1 = (64 + qbb) * 16 + ks;
            a0[c] = *(const int4*)((const char*)(Pacc + (size_t)u0 * 4096 + row6 * 64) + sch);
            a1[c] = *(const int4*)((const char*)(Pacc + (size_t)u1 * 4096 + row6 * 64) + sch);
            svs[c] = Psv[u0 * 64 + row6] + Psv[u1 * 64 + row6];
        }
    };
    auto writeA = [&](int buf) {                 // combine + normalize + ds_write
#pragma unroll
        for (int c = 0; c < 4; ++c) {
            int r = w * 32 + c * 8 + sr;
            float inv = 1.0f / svs[c];
            const unsigned short* e0 = (const unsigned short*)&a0[c];
            const unsigned short* e1 = (const unsigned short*)&a1[c];
            unsigned int wds[4];
#pragma unroll
            for (int i = 0; i < 4; ++i) {
                float x0 = (b2f(e0[2 * i])     + b2f(e1[2 * i]))     * inv;
                float x1 = (b2f(e0[2 * i + 1]) + b2f(e1[2 * i + 1])) * inv;
                asm("v_cvt_pk_bf16_f32 %0, %1, %2" : "=v"(wds[i]) : "v"(x0), "v"(x1));
            }
            int4 pk;
            pk.x = (int)wds[0]; pk.y = (int)wds[1]; pk.z = (int)wds[2]; pk.w = (int)wds[3];
            *(int4*)((char*)&As[buf][0] + r * 128 + (sch ^ ((r & 7) << 4))) = pk;
        }
    };
    auto stageB = [&](int buf, int ks) {
#pragma unroll
        for (int c = 0; c < 2; ++c) {
            int r0 = w * 16 + c * 8;
            int r = r0 + sr;
            gload16((const char*)&BT[(size_t)(n0 + r) * 1024 + ks * 64] + (sch ^ ((r & 7) << 4)),
                    (char*)&Bs[buf][0] + r0 * 128);
        }
    };

    int cur = 0;
    issueA(0);
    stageB(0, 0);
    writeA(0);
    __syncthreads();

    for (int ks = 0; ks < 16; ++ks) {
        if (ks + 1 < 16) { issueA(ks + 1); stageB(cur ^ 1, ks + 1); }
        const char* AsB = (const char*)&As[cur][0];
        const char* BsB = (const char*)&Bs[cur][0];
        __builtin_amdgcn_s_setprio(1);
#pragma unroll
        for (int kk = 0; kk < 2; ++kk) {
            short8 af[2], bf[4];
#pragma unroll
            for (int m = 0; m < 2; ++m) {
                int arow = w * 32 + m * 16 + lr;
                af[m] = *(const short8*)(AsB + arow * 128 +
                                         ((kk * 64 + lg * 16) ^ ((arow & 7) << 4)));
            }
#pragma unroll
            for (int n = 0; n < 4; ++n) {
                int brow = n * 16 + lr;
                bf[n] = *(const short8*)(BsB + brow * 128 +
                                         ((kk * 64 + lg * 16) ^ ((brow & 7) << 4)));
            }
#pragma unroll
            for (int m = 0; m < 2; ++m)
#pragma unroll
                for (int n = 0; n < 4; ++n)
                    acc[m][n] = __builtin_amdgcn_mfma_f32_16x16x32_bf16(af[m], bf[n], acc[m][n], 0, 0, 0);
        }
        __builtin_amdgcn_s_setprio(0);
        if (ks + 1 < 16) writeA(cur ^ 1);        // loads have aged under the MFMAs
        __syncthreads();                         // A visible + B landed + reads done
        cur ^= 1;
    }
#pragma unroll
    for (int m = 0; m < 2; ++m)
#pragma unroll
        for (int n = 0; n < 4; ++n)
#pragma unroll
            for (int rr = 0; rr < 4; ++rr) {
                int row = m0 + w * 32 + m * 16 + lg * 4 + rr;
                int col = n0 + n * 16 + lr;
                out[(size_t)row * 1024 + col] = acc[m][n][rr];
            }
}

// ---------------------------------------------------------------- launch

extern "C" void kernel_launch(void* const* d_in, const int* in_sizes, int n_in,
                              void* d_out, int out_size, void* d_ws, size_t ws_size,
                              hipStream_t stream) {
    const float* x  = (const float*)d_in[0];
    const float* Wq = (const float*)d_in[1];
    const float* Wk = (const float*)d_in[2];
    const float* Wv = (const float*)d_in[3];
    const float* Wo = (const float*)d_in[4];
    float* out = (float*)d_out;
    char* ws = (char*)d_ws;

    unsigned short* WT  = (unsigned short*)(ws + 0);          // [1536][1024] bf16, 3MB
    unsigned short* WoT = (unsigned short*)(ws + 3145728);    // [1024][1024], 2MB
    unsigned short* Qr  = (unsigned short*)(ws + 5242880);    // [16][4096][64], 8MB
    unsigned short* Kr  = (unsigned short*)(ws + 13631488);   // [4][4096][64], 2MB
    unsigned short* Vp  = (unsigned short*)(ws + 15728640);   // [4][64][4096] permuted, 2MB
    float* cs           = (float*)(ws + 26214400);            // [4096][32] x {cos,sin}, 1MB
    unsigned short* xb  = (unsigned short*)(ws + 27262976);   // [4096][1024], 8MB (dies after QKV)
    // attn partials overlay xb (dead by then):
    unsigned short* Pacc = (unsigned short*)(ws + 27262976);  // [2][64][16][64][64], 16.78MB
    float* Psv           = (float*)(ws + 44040192);           // [2][64][16][64], 0.5MB

    k_prep<<<dim3(32, 32, 6), 256, 0, stream>>>(Wq, Wk, Wv, Wo, x, WT, WoT, xb, cs);
    k_gemm_qkv<<<dim3(24, 32), 256, 0, stream>>>(xb, WT, cs, Qr, Kr, Vp);
    k_attn<<<dim3(32, 16, 2), 256, 0, stream>>>(Qr, Kr, Vp, Pacc, Psv);
    k_gemm_o<<<dim3(16, 32), 256, 0, stream>>>(Pacc, Psv, WoT, out);
}

// Round 14
// 114.621 us; speedup vs baseline: 1.2187x; 1.1165x over previous
//
#include <hip/hip_runtime.h>
#include <hip/hip_bf16.h>
#include <math.h>

typedef __attribute__((ext_vector_type(8))) short short8;
typedef __attribute__((ext_vector_type(4))) float f32x4;

#define S_   4096
#define HQ_  16
#define HKV_ 4
#define D_   64

static __device__ __forceinline__ unsigned short f2b(float f) {
    __hip_bfloat16 h = __float2bfloat16(f);
    return *reinterpret_cast<unsigned short*>(&h);
}
static __device__ __forceinline__ float b2f(unsigned short u) {
    union { unsigned int u; float f; } c;
    c.u = ((unsigned int)u) << 16;
    return c.f;
}

typedef __attribute__((address_space(1))) const unsigned int gas_u32;
typedef __attribute__((address_space(3))) unsigned int las_u32;
static __device__ __forceinline__ void gload16(const void* g, void* l) {
    __builtin_amdgcn_global_load_lds((gas_u32*)g, (las_u32*)l, 16, 0, 0);
}

// ---------------------------------------------------------------- prep (one kernel)
// z=0..3: weight transposes (Wq,Wk,Wv->WT; Wo->WoT), z=4: x->bf16, z=5: rope table.

__global__ __launch_bounds__(256) void k_prep(const float* __restrict__ Wq,
                                              const float* __restrict__ Wk,
                                              const float* __restrict__ Wv,
                                              const float* __restrict__ Wo,
                                              const float* __restrict__ x,
                                              unsigned short* __restrict__ WT,
                                              unsigned short* __restrict__ WoT,
                                              unsigned short* __restrict__ xb,
                                              float* __restrict__ cs) {
    const int z = blockIdx.z;
    const int t = threadIdx.x;
    if (z == 4) {                       // x -> bf16
        int flat = blockIdx.y * 32 + blockIdx.x;
#pragma unroll
        for (int ii = 0; ii < 4; ++ii) {
            int i = flat * 1024 + ii * 256 + t;
            float4 v = ((const float4*)x)[i];
            ushort4 o;
            o.x = f2b(v.x); o.y = f2b(v.y); o.z = f2b(v.z); o.w = f2b(v.w);
            ((ushort4*)xb)[i] = o;
        }
        return;
    }
    if (z == 5) {                       // rope table: 4096*32 entries
        int flat = blockIdx.y * 32 + blockIdx.x;
        if (flat >= 512) return;
        int i = flat * 256 + t;
        int s = i >> 5, jj = i & 31;
        float invf = exp2f(-(float)jj * (13.287712379549449f / 32.0f));
        float ang = (float)s * invf;
        ((float2*)cs)[i] = make_float2(cosf(ang), sinf(ang));
        return;
    }
    // weight transpose: out[N][K] bf16 = T(in[K][N] f32), K=1024
    const float* tin; unsigned short* tout; int N, gx;
    if (z == 0)      { tin = Wq; tout = WT;                 N = 1024; gx = 32; }
    else if (z == 1) { tin = Wk; tout = WT + 1024 * 1024;   N = 256;  gx = 8;  }
    else if (z == 2) { tin = Wv; tout = WT + 1280 * 1024;   N = 256;  gx = 8;  }
    else             { tin = Wo; tout = WoT;                N = 1024; gx = 32; }
    if ((int)blockIdx.x >= gx) return;
    __shared__ float tile[32][33];
    int tx = t & 31, ty = t >> 5;
    int n0 = blockIdx.x * 32, k0 = blockIdx.y * 32;
#pragma unroll
    for (int r = 0; r < 32; r += 8)
        tile[ty + r][tx] = tin[(size_t)(k0 + ty + r) * N + n0 + tx];
    __syncthreads();
#pragma unroll
    for (int r = 0; r < 32; r += 8)
        tout[(size_t)(n0 + ty + r) * 1024 + k0 + tx] = f2b(tile[tx][ty + r]);
}

// ---------------------------------------------------------------- QKV GEMM + fused RoPE/rearrange
// BM=128, BN=64 (one head per n-tile), BK=64, double-buffered 1-barrier
// pipeline. n-tiles 0..15: Q heads (RoPE + QS scale -> Qr), 16..19: K heads
// (RoPE -> Kr), 20..23: V heads -> Vp (kappa-permuted).

__global__ __launch_bounds__(256, 3)
void k_gemm_qkv(const unsigned short* __restrict__ A,   // xb [4096][1024]
                const unsigned short* __restrict__ BT,  // WT [1536][1024]
                const float* __restrict__ cs,
                unsigned short* __restrict__ Qr,
                unsigned short* __restrict__ Kr,
                unsigned short* __restrict__ Vp) {
    __shared__ unsigned short As[2][128 * 64];   // 2 x 16KB
    __shared__ unsigned short Bs[2][64 * 64];    // 2 x 8KB
    const int t = threadIdx.x;
    const int ntile = blockIdx.x;                 // 0..23
    const int n0 = ntile * 64;
    const int m0 = blockIdx.y * 128;
    const int w = t >> 6, lane = t & 63, lr = lane & 15, lg = lane >> 4;
    const int sr = lane >> 3, sch = (lane & 7) * 16;
    const int K = 1024;

    f32x4 acc[2][4];
#pragma unroll
    for (int m = 0; m < 2; ++m)
#pragma unroll
        for (int n = 0; n < 4; ++n) acc[m][n] = (f32x4){0.f, 0.f, 0.f, 0.f};

    auto stage = [&](int buf, int k0) {
#pragma unroll
        for (int c = 0; c < 4; ++c) {
            int r0 = w * 32 + c * 8;
            int r = r0 + sr;
            gload16((const char*)&A[(size_t)(m0 + r) * K + k0] + (sch ^ ((r & 7) << 4)),
                    (char*)&As[buf][0] + r0 * 128);
        }
#pragma unroll
        for (int c = 0; c < 2; ++c) {
            int r0 = w * 16 + c * 8;
            int r = r0 + sr;
            gload16((const char*)&BT[(size_t)(n0 + r) * K + k0] + (sch ^ ((r & 7) << 4)),
                    (char*)&Bs[buf][0] + r0 * 128);
        }
    };

    int cur = 0;
    stage(0, 0);
    __syncthreads();

    for (int k0 = 0; k0 < K; k0 += 64) {
        if (k0 + 64 < K) stage(cur ^ 1, k0 + 64);
        const char* AsB = (const char*)&As[cur][0];
        const char* BsB = (const char*)&Bs[cur][0];
        __builtin_amdgcn_s_setprio(1);
#pragma unroll
        for (int kk = 0; kk < 2; ++kk) {
            short8 af[2], bf[4];
#pragma unroll
            for (int m = 0; m < 2; ++m) {
                int arow = w * 32 + m * 16 + lr;
                af[m] = *(const short8*)(AsB + arow * 128 +
                                         ((kk * 64 + lg * 16) ^ ((arow & 7) << 4)));
            }
#pragma unroll
            for (int n = 0; n < 4; ++n) {
                int brow = n * 16 + lr;
                bf[n] = *(const short8*)(BsB + brow * 128 +
                                         ((kk * 64 + lg * 16) ^ ((brow & 7) << 4)));
            }
#pragma unroll
            for (int m = 0; m < 2; ++m)
#pragma unroll
                for (int n = 0; n < 4; ++n)
                    acc[m][n] = __builtin_amdgcn_mfma_f32_16x16x32_bf16(af[m], bf[n], acc[m][n], 0, 0, 0);
        }
        __builtin_amdgcn_s_setprio(0);
        __syncthreads();                          // reads done + prefetch landed
        cur ^= 1;
    }

    if (ntile < 20) {
        // RoPE epilogue. d pairs (d, d+32) = (acc[m][nt], acc[m][nt+2]), nt=0,1.
        const float QS = (ntile < 16) ? 0.125f * 1.44269504088896340736f : 1.0f;
        unsigned short* dst = (ntile < 16) ? (Qr + (size_t)ntile * (S_ * D_))
                                           : (Kr + (size_t)(ntile - 16) * (S_ * D_));
#pragma unroll
        for (int m = 0; m < 2; ++m)
#pragma unroll
            for (int rr = 0; rr < 4; ++rr) {
                int s = m0 + w * 32 + m * 16 + lg * 4 + rr;
                const float2* csr = (const float2*)cs + s * 32;
                float2 c0 = csr[lr];
                float2 c1 = csr[16 + lr];
                float t1 = acc[m][0][rr], t2 = acc[m][2][rr];
                dst[(size_t)s * 64 + lr]      = f2b((t1 * c0.x - t2 * c0.y) * QS);
                dst[(size_t)s * 64 + 32 + lr] = f2b((t2 * c0.x + t1 * c0.y) * QS);
                t1 = acc[m][1][rr]; t2 = acc[m][3][rr];
                dst[(size_t)s * 64 + 16 + lr] = f2b((t1 * c1.x - t2 * c1.y) * QS);
                dst[(size_t)s * 64 + 48 + lr] = f2b((t2 * c1.x + t1 * c1.y) * QS);
            }
    } else {
        int h2 = ntile - 20;
        unsigned short* dst = Vp + (size_t)h2 * (D_ * S_);
        // permuted store: s = m0 + w*32 + m*16 + lg*4 + rr  maps to
        // pos = m0 + (w>>1)*64 + (w&1)*32 + lg*8 + m*4 + rr  (rr contiguous)
#pragma unroll
        for (int m = 0; m < 2; ++m)
#pragma unroll
            for (int n = 0; n < 4; ++n) {
                int d = n * 16 + lr;
                int pos = m0 + (w >> 1) * 64 + (w & 1) * 32 + lg * 8 + m * 4;
                ushort4 o;
                o.x = f2b(acc[m][n][0]); o.y = f2b(acc[m][n][1]);
                o.z = f2b(acc[m][n][2]); o.w = f2b(acc[m][n][3]);
                *(ushort4*)&dst[(size_t)d * S_ + pos] = o;
            }
    }
}

// ---------------------------------------------------------------- Wo GEMM
// BM=128, BN=64, BK=64, double-buffered 1-barrier pipeline, f32 out.

__global__ __launch_bounds__(256, 3)
void k_gemm_o(const unsigned short* __restrict__ A,   // O [4096][1024]
              const unsigned short* __restrict__ BT,  // WoT [1024][1024]
              float* __restrict__ out) {
    __shared__ unsigned short As[2][128 * 64];
    __shared__ unsigned short Bs[2][64 * 64];
    const int t = threadIdx.x;
    const int n0 = blockIdx.x * 64;
    const int m0 = blockIdx.y * 128;
    const int w = t >> 6, lane = t & 63, lr = lane & 15, lg = lane >> 4;
    const int sr = lane >> 3, sch = (lane & 7) * 16;
    const int K = 1024;

    f32x4 acc[2][4];
#pragma unroll
    for (int m = 0; m < 2; ++m)
#pragma unroll
        for (int n = 0; n < 4; ++n) acc[m][n] = (f32x4){0.f, 0.f, 0.f, 0.f};

    auto stage = [&](int buf, int k0) {
#pragma unroll
        for (int c = 0; c < 4; ++c) {
            int r0 = w * 32 + c * 8;
            int r = r0 + sr;
            gload16((const char*)&A[(size_t)(m0 + r) * K + k0] + (sch ^ ((r & 7) << 4)),
                    (char*)&As[buf][0] + r0 * 128);
        }
#pragma unroll
        for (int c = 0; c < 2; ++c) {
            int r0 = w * 16 + c * 8;
            int r = r0 + sr;
            gload16((const char*)&BT[(size_t)(n0 + r) * K + k0] + (sch ^ ((r & 7) << 4)),
                    (char*)&Bs[buf][0] + r0 * 128);
        }
    };

    int cur = 0;
    stage(0, 0);
    __syncthreads();

    for (int k0 = 0; k0 < K; k0 += 64) {
        if (k0 + 64 < K) stage(cur ^ 1, k0 + 64);
        const char* AsB = (const char*)&As[cur][0];
        const char* BsB = (const char*)&Bs[cur][0];
        __builtin_amdgcn_s_setprio(1);
#pragma unroll
        for (int kk = 0; kk < 2; ++kk) {
            short8 af[2], bf[4];
#pragma unroll
            for (int m = 0; m < 2; ++m) {
                int arow = w * 32 + m * 16 + lr;
                af[m] = *(const short8*)(AsB + arow * 128 +
                                         ((kk * 64 + lg * 16) ^ ((arow & 7) << 4)));
            }
#pragma unroll
            for (int n = 0; n < 4; ++n) {
                int brow = n * 16 + lr;
                bf[n] = *(const short8*)(BsB + brow * 128 +
                                         ((kk * 64 + lg * 16) ^ ((brow & 7) << 4)));
            }
#pragma unroll
            for (int m = 0; m < 2; ++m)
#pragma unroll
                for (int n = 0; n < 4; ++n)
                    acc[m][n] = __builtin_amdgcn_mfma_f32_16x16x32_bf16(af[m], bf[n], acc[m][n], 0, 0, 0);
        }
        __builtin_amdgcn_s_setprio(0);
        __syncthreads();
        cur ^= 1;
    }
#pragma unroll
    for (int m = 0; m < 2; ++m)
#pragma unroll
        for (int n = 0; n < 4; ++n)
#pragma unroll
            for (int rr = 0; rr < 4; ++rr) {
                int row = m0 + w * 32 + m * 16 + lg * 4 + rr;
                int col = n0 + n * 16 + lr;
                out[(size_t)row * 1024 + col] = acc[m][n][rr];
            }
}

// ---------------------------------------------------------------- flash attention
// (verified best: 68 us, 0 bank conflicts, occ ~31%)
// Grid (32,16,2) = 1024 uniform blocks (4 blocks/CU, LDS 32KB). Block (p,h,j)
// handles q-blocks {63-p, p} (64 rows, 4 waves x 16 rows) -- triangle pairing.
// kv-tiles kb = j, j+2, ... (2-way K-split). Register-direct PV via permuted
// Vp (single b128 B-frag, K-read pattern). exp2-direct softmax.

__global__ __launch_bounds__(256, 4)
void k_attn(const unsigned short* __restrict__ Qr, // [HQ][S][D]
            const unsigned short* __restrict__ Kr, // [HKV][S][D]
            const unsigned short* __restrict__ Vp, // [HKV][D][S-permuted]
            unsigned short* __restrict__ Pacc,     // [2][64][16][64][64] bf16
            float* __restrict__ Psv) {             // [2][64][16][64]
    __shared__ unsigned short Ks[2][64 * 64];    // [kv][d], src-swizzled
    __shared__ unsigned short Vs[2][64 * 64];    // [d][kperm], src-swizzled

    const int t = threadIdx.x;
    const int p = blockIdx.x;                    // 0..31
    const int h = blockIdx.y;
    const int j = blockIdx.z;                    // K-split parity
    const int kvh = h >> 2;
    const int w = t >> 6, lane = t & 63, lr = lane & 15, lg = lane >> 4;

    const unsigned short* Qh = Qr + (size_t)h * (S_ * D_);
    const unsigned short* Kh = Kr + (size_t)kvh * (S_ * D_);
    const unsigned short* Vh = Vp + (size_t)kvh * (D_ * S_);

    const int xw = (lr & 7) << 4;
    const int sr = lane >> 3, sch = (lane & 7) * 16;
    const int r0a = w * 16, r0b = w * 16 + 8;

#pragma unroll 1
    for (int half = 0; half < 2; ++half) {
        const int qb = half ? p : (63 - p);
        const int tend = qb + 1;                 // kv tiles: 0..qb
        const int qi = qb * 64 + w * 16 + lr;    // this lane's q-row

        const char* kp[2];
        const char* vp[2];
        {
            int ra = r0a + sr, rb = r0b + sr;
            kp[0] = (const char*)(Kh + (size_t)(j * 64 + ra) * 64) + (sch ^ ((ra & 7) << 4));
            kp[1] = (const char*)(Kh + (size_t)(j * 64 + rb) * 64) + (sch ^ ((rb & 7) << 4));
            vp[0] = (const char*)(Vh + (size_t)ra * S_ + j * 64) + (sch ^ ((ra & 7) << 4));
            vp[1] = (const char*)(Vh + (size_t)rb * S_ + j * 64) + (sch ^ ((rb & 7) << 4));
        }
        auto stage = [&](int buf) {
            gload16(kp[0], (char*)&Ks[buf][0] + r0a * 128);
            gload16(kp[1], (char*)&Ks[buf][0] + r0b * 128);
            gload16(vp[0], (char*)&Vs[buf][0] + r0a * 128);
            gload16(vp[1], (char*)&Vs[buf][0] + r0b * 128);
            kp[0] += 16384; kp[1] += 16384;      // +128 keys (2 tiles)
            vp[0] += 256;   vp[1] += 256;        // +128 key-positions
        };

        short8 aq[2];
        {
            int qrow = qb * 64 + w * 16 + lr;
            aq[0] = *(const short8*)&Qh[(size_t)qrow * 64 + lg * 8];
            aq[1] = *(const short8*)&Qh[(size_t)qrow * 64 + 32 + lg * 8];
        }
        float svl = 0.f;
        f32x4 acc_o[4];
#pragma unroll
        for (int i = 0; i < 4; ++i) acc_o[i] = (f32x4){0.f, 0.f, 0.f, 0.f};

        int cur = 0;
        stage(0);
        __syncthreads();

        for (int kb = j; kb < tend; kb += 2) {
            if (kb + 2 < tend) stage(cur ^ 1);

            // ---- S^T = K Q^T: s[nt] = P[k=nt*16+lg*4+r][q=lr]
            f32x4 s[4];
#pragma unroll
            for (int i = 0; i < 4; ++i) s[i] = (f32x4){0.f, 0.f, 0.f, 0.f};
            const char* KsB = (const char*)&Ks[cur][0];
            __builtin_amdgcn_s_setprio(1);
#pragma unroll
            for (int kk = 0; kk < 2; ++kk)
#pragma unroll
                for (int nt = 0; nt < 4; ++nt) {
                    short8 kf = *(const short8*)(KsB + (nt * 16 + lr) * 128 + ((kk * 64 + lg * 16) ^ xw));
                    s[nt] = __builtin_amdgcn_mfma_f32_16x16x32_bf16(kf, aq[kk], s[nt], 0, 0, 0);
                }
            __builtin_amdgcn_s_setprio(0);

            // ---- causal mask on diagonal tile
            if (kb == qb) {
                int kbase = kb * 64 + lg * 4;
#pragma unroll
                for (int nt = 0; nt < 4; ++nt)
#pragma unroll
                    for (int rr = 0; rr < 4; ++rr)
                        if (kbase + nt * 16 + rr > qi) s[nt][rr] = -INFINITY;
            }

            // ---- p = exp2(s), pack in-lane (A-frag words, kappa order), sum
            unsigned int wd[8];
#pragma unroll
            for (int nt = 0; nt < 4; ++nt) {
                float p0 = exp2f(s[nt][0]), p1 = exp2f(s[nt][1]);
                float p2 = exp2f(s[nt][2]), p3 = exp2f(s[nt][3]);
                svl += (p0 + p1) + (p2 + p3);
                asm("v_cvt_pk_bf16_f32 %0, %1, %2" : "=v"(wd[nt * 2])     : "v"(p0), "v"(p1));
                asm("v_cvt_pk_bf16_f32 %0, %1, %2" : "=v"(wd[nt * 2 + 1]) : "v"(p2), "v"(p3));
            }

            // ---- O += P V  (kappa-ordered contraction; single b128 B-frag)
            const char* VsB = (const char*)&Vs[cur][0];
            __builtin_amdgcn_s_setprio(1);
#pragma unroll
            for (int kk = 0; kk < 2; ++kk) {
                union { unsigned int u[4]; short8 s8; } pa;
                pa.u[0] = wd[4 * kk + 0]; pa.u[1] = wd[4 * kk + 1];
                pa.u[2] = wd[4 * kk + 2]; pa.u[3] = wd[4 * kk + 3];
#pragma unroll
                for (int nt = 0; nt < 4; ++nt) {
                    short8 vb = *(const short8*)(VsB + (nt * 16 + lr) * 128 + ((kk * 64 + lg * 16) ^ xw));
                    acc_o[nt] = __builtin_amdgcn_mfma_f32_16x16x32_bf16(pa.s8, vb, acc_o[nt], 0, 0, 0);
                }
            }
            __builtin_amdgcn_s_setprio(0);

            __syncthreads();                     // buf free + prefetch landed
            cur ^= 1;
        }

        // ---- epilogue: reduce row sum once, write partials
        svl += __shfl_xor(svl, 16);
        svl += __shfl_xor(svl, 32);
        const int u = ((j * 64 + qb) * 16 + h);
        if (lg == 0) Psv[u * 64 + w * 16 + lr] = svl;
        unsigned short* Pb = Pacc + (size_t)u * 4096;
#pragma unroll
        for (int nt = 0; nt < 4; ++nt) {
            int rr = w * 16 + lg * 4;
            int col = nt * 16 + lr;
            Pb[(rr + 0) * 64 + col] = f2b(acc_o[nt][0]);
            Pb[(rr + 1) * 64 + col] = f2b(acc_o[nt][1]);
            Pb[(rr + 2) * 64 + col] = f2b(acc_o[nt][2]);
            Pb[(rr + 3) * 64 + col] = f2b(acc_o[nt][3]);
        }
    }
}

// ---------------------------------------------------------------- combine splits

__global__ __launch_bounds__(256) void k_combine(const unsigned short* __restrict__ Pacc,
                                                 const float* __restrict__ Psv,
                                                 unsigned short* __restrict__ O) {
    const int qb = blockIdx.x, h = blockIdx.y;
    const int t = threadIdx.x;
    const int r = t >> 2, db = (t & 3) * 16;
    const int u0 = (qb * 16 + h);
    const int u1 = ((64 + qb) * 16 + h);
    float sa = Psv[u0 * 64 + r], sb = Psv[u1 * 64 + r];
    float inv = 1.f / (sa + sb);
    const unsigned short* A_ = Pacc + (size_t)u0 * 4096 + r * 64 + db;
    const unsigned short* B_ = Pacc + (size_t)u1 * 4096 + r * 64 + db;
    unsigned short* Op = O + (size_t)(qb * 64 + r) * 1024 + h * 64 + db;
#pragma unroll
    for (int halfv = 0; halfv < 2; ++halfv) {
        short8 va = *(const short8*)(A_ + halfv * 8);
        short8 vb = *(const short8*)(B_ + halfv * 8);
        short8 o;
#pragma unroll
        for (int i = 0; i < 8; ++i)
            o[i] = (short)f2b((b2f((unsigned short)va[i]) + b2f((unsigned short)vb[i])) * inv);
        *(short8*)(Op + halfv * 8) = o;
    }
}

// ---------------------------------------------------------------- launch

extern "C" void kernel_launch(void* const* d_in, const int* in_sizes, int n_in,
                              void* d_out, int out_size, void* d_ws, size_t ws_size,
                              hipStream_t stream) {
    const float* x  = (const float*)d_in[0];
    const float* Wq = (const float*)d_in[1];
    const float* Wk = (const float*)d_in[2];
    const float* Wv = (const float*)d_in[3];
    const float* Wo = (const float*)d_in[4];
    float* out = (float*)d_out;
    char* ws = (char*)d_ws;

    unsigned short* WT  = (unsigned short*)(ws + 0);          // [1536][1024] bf16, 3MB
    unsigned short* WoT = (unsigned short*)(ws + 3145728);    // [1024][1024], 2MB
    unsigned short* Qr  = (unsigned short*)(ws + 5242880);    // [16][4096][64], 8MB
    unsigned short* Kr  = (unsigned short*)(ws + 13631488);   // [4][4096][64], 2MB
    unsigned short* Vp  = (unsigned short*)(ws + 15728640);   // [4][64][4096] permuted, 2MB
    unsigned short* O   = (unsigned short*)(ws + 17825792);   // [4096][1024], 8MB
    float* cs           = (float*)(ws + 26214400);            // [4096][32] x {cos,sin}, 1MB
    unsigned short* xb  = (unsigned short*)(ws + 27262976);   // [4096][1024], 8MB (dies after QKV)
    // attn partials overlay xb (dead by then):
    unsigned short* Pacc = (unsigned short*)(ws + 27262976);  // [2][64][16][64][64], 16.78MB
    float* Psv           = (float*)(ws + 44040192);           // [2][64][16][64], 0.5MB

    k_prep<<<dim3(32, 32, 6), 256, 0, stream>>>(Wq, Wk, Wv, Wo, x, WT, WoT, xb, cs);
    k_gemm_qkv<<<dim3(24, 32), 256, 0, stream>>>(xb, WT, cs, Qr, Kr, Vp);
    k_attn<<<dim3(32, 16, 2), 256, 0, stream>>>(Qr, Kr, Vp, Pacc, Psv);
    k_combine<<<dim3(64, 16), 256, 0, stream>>>(Pacc, Psv, O);
    k_gemm_o<<<dim3(16, 32), 256, 0, stream>>>(O, WoT, out);
}